// Round 11
// baseline (179.955 us; speedup 1.0000x reference)
//
#include <hip/hip_runtime.h>

#define NCLS  80
#define SELK  256           // histogram cutoff target rank (consumption <= ~210/level)
#define NLVL  3
#define NIMG  8
#define DETS  100
#define CAP   512           // per-pair collect capacity == sort segment width
#define NDEC  512           // ranks decoded for NMS (consumed ~210; 2.4x margin)
#define HBINS 4096          // q-space bins, 8192-ulp granules
#define NHBLK 16            // hist blocks per (img,level) pair
#define NCBLK 16            // collect blocks per (img,level) pair
#define QBASE 0x3F800000u   // bits of q = 1.0 (q > 1 always)
#define QMAX  0x41C80000u   // bits of 25.0; q < 25  <=>  s > 0.2
#define IMGSZ 2048.0f

// ---------------- helpers ----------------

__device__ __forceinline__ float sigm(float x) {
    if (x >= 0.f) return 1.f / (1.f + expf(-x));
    float e = expf(x);
    return e / (1.f + e);
}

// q = (1+e^-a)(1+e^-b), rounding pinned (identical bits in k_hist and k_collect)
__device__ __forceinline__ unsigned int qbits(float ea, float t1) {
    return __float_as_uint(__fmul_rn(__fadd_rn(1.f, ea), t1));
}

__device__ __forceinline__ void lvl_select(int level,
    const float* c0, const float* c1, const float* c2,
    const float* t0, const float* t1, const float* t2,
    const float** cls, const float** ctr, int* hw) {
    if (level == 0)      { *cls = c0; *ctr = t0; *hw = 4096; }
    else if (level == 1) { *cls = c1; *ctr = t1; *hw = 1024; }
    else                 { *cls = c2; *ctr = t2; *hw = 256; }
}

// ---------------- stage 1: per-block partial histograms of q bits ----------------
// (also zeroes the collect counters; visibility via kernel boundary, NO fences:
//  round-7 postmortem showed device-scope __threadfence fusion costs ~170 us)

__global__ void k_hist(const float* c0, const float* c1, const float* c2,
                       const float* t0, const float* t1, const float* t2,
                       unsigned int* parts, unsigned int* counters) {
    int level = blockIdx.z, img = blockIdx.y;
    int pair = img * NLVL + level;
    if (blockIdx.x == 0 && threadIdx.x == 0) counters[pair * 16] = 0;
    const float* cls; const float* ctr; int hw;
    lvl_select(level, c0, c1, c2, t0, t1, t2, &cls, &ctr, &hw);
    int n4 = hw * (NCLS / 4);          // float4 granules; 4 classes share one anchor
    const float4* cl4 = (const float4*)(cls + (size_t)img * hw * NCLS);
    const float* ct = ctr + (size_t)img * hw;
    __shared__ unsigned int h[HBINS];
    for (int i = threadIdx.x; i < HBINS; i += 256) h[i] = 0;
    __syncthreads();
    for (int i = blockIdx.x * 256 + threadIdx.x; i < n4; i += NHBLK * 256) {
        float4 v = cl4[i];
        int a = i / (NCLS / 4);        // 20 float4 per anchor row
        float eb = expf(-ct[a]);
        float t1 = __fadd_rn(1.f, eb);
        #pragma unroll
        for (int k = 0; k < 4; ++k) {
            float x = (k == 0) ? v.x : (k == 1) ? v.y : (k == 2) ? v.z : v.w;
            unsigned int qb = qbits(expf(-x), t1);
            if (qb < QMAX) {
                unsigned int bin = (qb - QBASE) >> 13;
                if (bin > HBINS - 1) bin = HBINS - 1;
                atomicAdd(&h[bin], 1u);
            }
        }
    }
    __syncthreads();
    unsigned int* P = parts + ((size_t)(pair * NHBLK + blockIdx.x)) * HBINS;
    for (int i = threadIdx.x; i < HBINS; i += 256) P[i] = h[i];   // coalesced, no atomics
}

// ---------------- stage 2 (fused): in-block cutoff find + collect ----------------
// Each block merges the 16 partials and computes V itself (identical result in
// every block — pure function of parts). Survivors staged in LDS (fast local
// atomics), ONE global atomic per block (round-4: per-element device atomics
// serialized ~85 us). Key is GLOBALLY comparable:
// (score_bits << 32) | ~((level<<19)|e) — for equal score bits the reference
// global order is (level asc, flat-index asc). Slot order in buf is irrelevant.

__global__ void k_collect(const float* c0, const float* c1, const float* c2,
                          const float* t0, const float* t1, const float* t2,
                          const unsigned int* parts, unsigned int* counters,
                          unsigned long long* buf) {
    int level = blockIdx.z, img = blockIdx.y;
    int pair = img * NLVL + level;
    int tid = threadIdx.x;
    __shared__ unsigned int hb[HBINS];          // 16 KB merged hist
    __shared__ unsigned int segsum[256];
    __shared__ unsigned int pref[256];
    __shared__ unsigned long long sbuf[CAP];    // 4 KB survivor staging
    __shared__ unsigned int scnt, sbase, Vsh;
    if (tid == 0) scnt = 0;
    // merge the 16 partials (coalesced: thread t reads bin t+256j of each)
    {
        unsigned int acc[HBINS / 256];
        #pragma unroll
        for (int j = 0; j < HBINS / 256; ++j) acc[j] = 0;
        for (int blk = 0; blk < NHBLK; ++blk) {
            const unsigned int* P = parts + ((size_t)(pair * NHBLK + blk)) * HBINS;
            #pragma unroll
            for (int j = 0; j < HBINS / 256; ++j) acc[j] += P[tid + 256 * j];
        }
        #pragma unroll
        for (int j = 0; j < HBINS / 256; ++j) hb[tid + 256 * j] = acc[j];
    }
    __syncthreads();
    // scan: q ascending == score descending; find bin bracketing rank SELK
    {
        unsigned int seg = 0;
        #pragma unroll
        for (int j = 0; j < 16; ++j) seg += hb[16 * tid + j];
        segsum[tid] = seg;
        pref[tid] = seg;
        __syncthreads();
        for (int off = 1; off < 256; off <<= 1) {
            unsigned int v = (tid >= off) ? pref[tid - off] : 0u;
            __syncthreads();
            pref[tid] += v;
            __syncthreads();
        }
        unsigned int incl = pref[tid];
        unsigned int excl = incl - segsum[tid];
        if (excl < (unsigned int)SELK && incl >= (unsigned int)SELK) {
            unsigned int cum = excl; int B = HBINS - 1;
            for (int b = 16 * tid; b < 16 * tid + 16; ++b) {
                cum += hb[b];
                if (cum >= (unsigned int)SELK) { B = b; break; }
            }
            Vsh = (B >= HBINS - 1) ? QMAX : (QBASE + ((unsigned int)(B + 1) << 13));
        }
        if (tid == 255 && pref[255] < (unsigned int)SELK)
            Vsh = QMAX;   // fewer than SELK pass threshold: collect all passing
    }
    __syncthreads();
    unsigned int V = Vsh;

    const float* cls; const float* ctr; int hw;
    lvl_select(level, c0, c1, c2, t0, t1, t2, &cls, &ctr, &hw);
    int n4 = hw * (NCLS / 4);
    const float4* cl4 = (const float4*)(cls + (size_t)img * hw * NCLS);
    const float* ct = ctr + (size_t)img * hw;
    for (int i = blockIdx.x * 256 + tid; i < n4; i += NCBLK * 256) {
        float4 v = cl4[i];
        int a = i / (NCLS / 4);
        float cta = ct[a];
        float eb = expf(-cta);
        float t1 = __fadd_rn(1.f, eb);
        #pragma unroll
        for (int k = 0; k < 4; ++k) {
            float x = (k == 0) ? v.x : (k == 1) ? v.y : (k == 2) ? v.z : v.w;
            unsigned int qb = qbits(expf(-x), t1);
            if (qb < V) {
                // exact score, bit-identical to rounds 1-10 (validated absmax 0.0)
                float s = sqrtf(sigm(x) * sigm(cta));
                unsigned int e = (unsigned int)(4 * i + k);          // < 2^19
                unsigned int p = ((unsigned int)level << 19) | e;    // 21-bit tie word
                unsigned int slot = atomicAdd(&scnt, 1u);   // LDS atomic, sparse
                if (slot < CAP)
                    sbuf[slot] = ((unsigned long long)__float_as_uint(s) << 32) | (~p);
            }
        }
    }
    __syncthreads();
    unsigned int cl_n = scnt; if (cl_n > CAP) cl_n = CAP;
    if (tid == 0)
        sbase = atomicAdd(&counters[pair * 16], cl_n);      // one global atomic/block
    __syncthreads();
    unsigned int base = sbase;
    for (unsigned int idx = tid; idx < cl_n; idx += 256) {
        unsigned int g = base + idx;
        if (g < CAP) buf[(size_t)pair * CAP + g] = sbuf[idx];   // coalesced flush
    }
}

// ---------------- stage 3 (fused): segmented sort + merge-path + decode + NMS ----------------
// One block (512 thr, 8 waves) per image. Round-10 postmortem: the sort cost is
// BARRIER LATENCY (55 phases x 16 waves, 8 CUs active). Now: 512-wide segments
// (45 phases) and wave-synchronous phases — thread==segment-index, so j<=32
// exchanges stay inside one wave's 64-element span: volatile LDS + lockstep,
// NO __syncthreads. Barriers only around cross-wave phases (j>=64): 9 total.

__global__ void __launch_bounds__(512)
k_merge_nms(const unsigned long long* buf, const unsigned int* counters,
            const float* r0, const float* r1, const float* r2,
            const float* a0, const float* a1, const float* a2,
            float* out) {
    int img = blockIdx.x;
    int tid = threadIdx.x;
    __shared__ unsigned long long S[3 * CAP];     // 12 KB: A|B|C; A-region becomes R
    __shared__ unsigned long long Mbuf[2 * CAP];  // 8 KB: merge(A,B); later wbox
    __shared__ float4 sbx[64]; __shared__ float sar[64];
    __shared__ float4 koff[DETS]; __shared__ float karr[DETS];
    __shared__ float4 kb[DETS]; __shared__ float ks[DETS]; __shared__ int kl[DETS];
    __shared__ float4 rb[DETS]; __shared__ int rl[DETS];
    float4* wbox = (float4*)Mbuf;                 // alias: valid after M is dead
    int*    wlab = (int*)(S + CAP);               // alias: B-region, dead after R

    // load the three pools (tid covers 0..CAP-1)
    for (int l = 0; l < NLVL; ++l) {
        int pair = img * NLVL + l;
        int c = (int)counters[pair * 16]; if (c > CAP) c = CAP;
        const unsigned long long* B = buf + (size_t)pair * CAP;
        S[l * CAP + tid] = (tid < c) ? B[tid] : 0ull;
    }
    __syncthreads();
    // segmented bitonic, wave-synchronous where possible
    {
        volatile unsigned long long* vS = S;
        bool prev_cross = false;
        for (int k2 = 2; k2 <= CAP; k2 <<= 1) {
            for (int j = k2 >> 1; j > 0; j >>= 1) {
                bool cross = (j >= 64);
                if (cross || prev_cross) __syncthreads();
                int i = tid, ixj = i ^ j;
                if (ixj > i) {
                    bool up = ((i & k2) == 0);
                    #pragma unroll
                    for (int seg = 0; seg < NLVL; ++seg) {
                        int base = seg * CAP;
                        unsigned long long a = vS[base + i], b = vS[base + ixj];
                        if (up ? (a < b) : (a > b)) { vS[base + i] = b; vS[base + ixj] = a; }
                    }
                }
                prev_cross = cross;
            }
        }
    }
    __syncthreads();
    // merge-path A (512) + B (512) -> M (1024), descending, keys unique
    for (int k = tid; k < 2 * CAP; k += 512) {
        int lo = max(0, k - CAP), hi = min(k, CAP);
        while (lo < hi) {
            int mid = (lo + hi) >> 1;
            if (S[mid] > S[CAP + (k - mid - 1)]) lo = mid + 1; else hi = mid;
        }
        int i = lo, j = k - lo;
        unsigned long long av = (i < CAP) ? S[i] : 0ull;
        unsigned long long bv = (j < CAP) ? S[CAP + j] : 0ull;
        Mbuf[k] = (av > bv) ? av : bv;
    }
    __syncthreads();
    // top-512 of merge(M (1024), C (512)) -> R (= A-region, dead)
    {
        int k = tid;
        int lo = max(0, k - CAP), hi = k;   // hi = min(k, 2*CAP) = k
        while (lo < hi) {
            int mid = (lo + hi) >> 1;
            if (Mbuf[mid] > S[2 * CAP + (k - mid - 1)]) lo = mid + 1; else hi = mid;
        }
        int i = lo, j = k - lo;
        unsigned long long mv = (i < 2 * CAP) ? Mbuf[i] : 0ull;
        unsigned long long cv = (j < CAP) ? S[2 * CAP + j] : 0ull;
        unsigned long long rk = (mv > cv) ? mv : cv;
        __syncthreads();                    // all merge reads done before R write
        S[k] = rk;
    }
    __syncthreads();
    // lazy decode of the top NDEC ranks (one thread per rank; gathers anc+reg)
    {
        unsigned long long key = S[tid];
        float4 b4 = make_float4(0.f, 0.f, 0.f, 0.f); int lbv = 0;
        if (key != 0ull) {
            unsigned int p = (~((unsigned int)key)) & 0x1FFFFFu;
            int lvl = (int)(p >> 19);
            unsigned int e = p & 0x7FFFFu;
            int a = (int)(e / NCLS); lbv = (int)(e % NCLS);
            const float* anc; const float* reg; int hw;
            if (lvl == 0)      { anc = a0; reg = r0; hw = 4096; }
            else if (lvl == 1) { anc = a1; reg = r1; hw = 1024; }
            else               { anc = a2; reg = r2; hw = 256; }
            const float* rg = reg + (size_t)img * hw * 4;
            float ax1 = anc[a * 4 + 0], ay1 = anc[a * 4 + 1];
            float ax2 = anc[a * 4 + 2], ay2 = anc[a * 4 + 3];
            float cx = 0.5f * (ax1 + ax2), cy = 0.5f * (ay1 + ay2);
            float w = ax2 - ax1, h = ay2 - ay1;
            float e0 = rg[a * 4 + 0] * w, e1 = rg[a * 4 + 1] * h;
            float e2 = rg[a * 4 + 2] * w, e3 = rg[a * 4 + 3] * h;
            b4.x = fminf(fmaxf(cx - e0, 0.f), IMGSZ);
            b4.y = fminf(fmaxf(cy - e1, 0.f), IMGSZ);
            b4.z = fminf(fmaxf(cx + e2, 0.f), IMGSZ);
            b4.w = fminf(fmaxf(cy + e3, 0.f), IMGSZ);
        }
        wbox[tid] = b4; wlab[tid] = lbv;    // Mbuf / B-region: both dead
    }
    __syncthreads();

    if (tid >= 64) return;   // single wave finishes (batched, short)
    int lane = tid;
    unsigned long long lmask_lt = (lane == 0) ? 0ull : (~0ull >> (64 - lane));

    int kept = 0, ring = 0, r = 0;

    while (kept < DETS && r < NDEC) {
        int rank = r + lane;
        unsigned long long key = (rank < NDEC) ? S[rank] : 0ull;
        unsigned int bits = (unsigned int)(key >> 32);
        unsigned long long pm = __ballot(bits != 0u);   // positives form a prefix (sorted)
        int npos = (pm == ~0ull) ? 64 : (int)__builtin_ctzll(~pm);
        if (npos == 0) break;                           // negatives from rank r onward

        float4 bx = make_float4(0.f, 0.f, 0.f, 0.f); int lb = 0;
        if (lane < npos) { bx = wbox[rank]; lb = wlab[rank]; }
        float off = (float)lb * (IMGSZ + 1.0f);
        float ox1 = bx.x + off, oy1 = bx.y + off;
        float ox2 = bx.z + off, oy2 = bx.w + off;
        float car = (ox2 - ox1) * (oy2 - oy1);
        sbx[lane] = make_float4(ox1, oy1, ox2, oy2);
        sar[lane] = car;        // single wave: program-order LDS, no barrier needed

        // (1) vs previously-kept boxes (broadcast reads, parallel across lanes)
        bool supk = false;
        for (int k2 = 0; k2 < kept; ++k2) {
            float4 kk = koff[k2]; float ka = karr[k2];
            float lx = fmaxf(kk.x, ox1), ly = fmaxf(kk.y, oy1);
            float rx = fminf(kk.z, ox2), ry = fminf(kk.w, oy2);
            float w = fmaxf(rx - lx, 0.f), h = fmaxf(ry - ly, 0.f);
            float inter = w * h;
            supk = supk || (inter / (ka + car - inter) > 0.6f);
        }
        // (2) intra-batch column mask: who among earlier slots suppresses me
        unsigned long long col = 0ull;
        for (int i = 0; i < npos; ++i) {
            float4 c = sbx[i]; float ca = sar[i];
            float lx = fmaxf(c.x, ox1), ly = fmaxf(c.y, oy1);
            float rx = fminf(c.z, ox2), ry = fminf(c.w, oy2);
            float w = fmaxf(rx - lx, 0.f), h = fmaxf(ry - ly, 0.f);
            float inter = w * h;
            if ((inter / (ca + car - inter) > 0.6f) && (i < lane)) col |= (1ull << i);
        }
        // (3) wave-uniform greedy resolve (picks are in increasing slot order)
        unsigned long long undecided = __ballot((lane < npos) && !supk);
        unsigned long long aliveSel = 0ull;
        int capleft = DETS - kept;
        int lastSlot = npos - 1;
        while (undecided) {
            int i = (int)__builtin_ctzll(undecided);
            aliveSel |= (1ull << i);
            undecided &= ~(1ull << i);
            if (--capleft == 0) { lastSlot = i; break; }   // kept hits 100 at slot i
            unsigned long long row = __ballot(((col >> i) & 1ull) != 0ull);
            undecided &= ~row;
        }
        unsigned long long region = (lastSlot >= 63) ? ~0ull : ((1ull << (lastSlot + 1)) - 1ull);
        region &= (npos >= 64) ? ~0ull : ((1ull << npos) - 1ull);
        unsigned long long rejm = region & ~aliveSel;

        if ((aliveSel >> lane) & 1ull) {
            int ki = kept + (int)__popcll(aliveSel & lmask_lt);
            koff[ki] = make_float4(ox1, oy1, ox2, oy2); karr[ki] = car;
            kb[ki] = bx; ks[ki] = __uint_as_float(bits); kl[ki] = lb;
        }
        if ((rejm >> lane) & 1ull) {
            int ri = ring + (int)__popcll(rejm & lmask_lt);
            if (ri < DETS) { rb[ri] = bx; rl[ri] = lb; }
        }
        kept += (int)__popcll(aliveSel);
        ring += (int)__popcll(rejm);
        r += lastSlot + 1;
    }

    // negative / padding fill: remaining ranks in order until ring >= DETS
    while (kept < DETS && ring < DETS && r < NDEC) {
        int rank = r + lane;
        if (rank < NDEC) {
            int ri = ring + lane;
            if (ri < DETS) { rb[ri] = wbox[rank]; rl[ri] = wlab[rank]; }
        }
        int take = NDEC - r; if (take > 64) take = 64;
        ring += take;
        r += 64;
    }

    for (int k = lane; k < DETS; k += 64) {
        float4 bxo; float scv; int lv;
        if (k < kept) { bxo = kb[k]; scv = ks[k]; lv = kl[k]; }
        else { int q = k - kept; bxo = rb[q]; scv = -1.0f; lv = rl[q]; }
        float* ob = out + ((size_t)img * DETS + k) * 4;
        ob[0] = bxo.x; ob[1] = bxo.y; ob[2] = bxo.z; ob[3] = bxo.w;
        out[NIMG * DETS * 4 + img * DETS + k] = scv;
        out[NIMG * DETS * 5 + img * DETS + k] = (float)lv;
    }
}

// ---------------- launch ----------------

extern "C" void kernel_launch(void* const* d_in, const int* in_sizes, int n_in,
                              void* d_out, int out_size, void* d_ws, size_t ws_size,
                              hipStream_t stream) {
    (void)in_sizes; (void)n_in; (void)out_size; (void)ws_size;
    // setup_inputs() dict order: cls0, reg0, ctr0, anc0, cls1, reg1, ctr1, anc1, cls2, reg2, ctr2, anc2
    const float* cls0 = (const float*)d_in[0];
    const float* reg0 = (const float*)d_in[1];
    const float* ctr0 = (const float*)d_in[2];
    const float* anc0 = (const float*)d_in[3];
    const float* cls1 = (const float*)d_in[4];
    const float* reg1 = (const float*)d_in[5];
    const float* ctr1 = (const float*)d_in[6];
    const float* anc1 = (const float*)d_in[7];
    const float* cls2 = (const float*)d_in[8];
    const float* reg2 = (const float*)d_in[9];
    const float* ctr2 = (const float*)d_in[10];
    const float* anc2 = (const float*)d_in[11];
    float* out = (float*)d_out;
    char* ws = (char*)d_ws;

    // workspace layout (bytes)
    const size_t OFF_PARTS = 0;          // 24*16*4096*4 = 6,291,456 (fully overwritten)
    const size_t OFF_CNT   = 6291456;    // 24 counters, 64B apart = 1536 (zeroed by k_hist)
    const size_t OFF_BUF   = 6292992;    // 24*512*8 = 98,304 -> total 6,391,296

    unsigned int* parts = (unsigned int*)(ws + OFF_PARTS);
    unsigned int* cnt   = (unsigned int*)(ws + OFF_CNT);
    unsigned long long* buf = (unsigned long long*)(ws + OFF_BUF);

    k_hist<<<dim3(NHBLK, NIMG, NLVL), 256, 0, stream>>>(
        cls0, cls1, cls2, ctr0, ctr1, ctr2, parts, cnt);
    k_collect<<<dim3(NCBLK, NIMG, NLVL), 256, 0, stream>>>(
        cls0, cls1, cls2, ctr0, ctr1, ctr2, parts, cnt, buf);
    k_merge_nms<<<NIMG, 512, 0, stream>>>(buf, cnt, reg0, reg1, reg2,
                                          anc0, anc1, anc2, out);
}

// Round 12
// 163.097 us; speedup vs baseline: 1.1034x; 1.1034x over previous
//
#include <hip/hip_runtime.h>

#define NCLS  80
#define SELK  256           // histogram cutoff target rank (consumption <= ~210/level)
#define NLVL  3
#define NIMG  8
#define DETS  100
#define CAP   512           // per-pair collect capacity == sort segment width
#define NDEC  512           // ranks decoded for NMS
#define NMSW  256           // ranks with precomputed pairwise masks (consumed ~210 max)
#define HBINS 4096          // q-space bins, 8192-ulp granules
#define NHBLK 16            // hist blocks per (img,level) pair
#define NCBLK 16            // collect blocks per (img,level) pair
#define QBASE 0x3F800000u   // bits of q = 1.0 (q > 1 always)
#define QMAX  0x41C80000u   // bits of 25.0; q < 25  <=>  s > 0.2
#define IMGSZ 2048.0f

// ---------------- helpers ----------------

__device__ __forceinline__ float sigm(float x) {
    if (x >= 0.f) return 1.f / (1.f + expf(-x));
    float e = expf(x);
    return e / (1.f + e);
}

// q = (1+e^-a)(1+e^-b), rounding pinned (identical bits in k_hist and k_collect)
__device__ __forceinline__ unsigned int qbits(float ea, float t1) {
    return __float_as_uint(__fmul_rn(__fadd_rn(1.f, ea), t1));
}

__device__ __forceinline__ unsigned long long shfl_u64(unsigned long long v, int lane) {
    int lo = (int)(unsigned int)v;
    int hi = (int)(unsigned int)(v >> 32);
    lo = __shfl(lo, lane, 64);
    hi = __shfl(hi, lane, 64);
    return ((unsigned long long)(unsigned int)hi << 32) | (unsigned int)lo;
}

__device__ __forceinline__ void lvl_select(int level,
    const float* c0, const float* c1, const float* c2,
    const float* t0, const float* t1, const float* t2,
    const float** cls, const float** ctr, int* hw) {
    if (level == 0)      { *cls = c0; *ctr = t0; *hw = 4096; }
    else if (level == 1) { *cls = c1; *ctr = t1; *hw = 1024; }
    else                 { *cls = c2; *ctr = t2; *hw = 256; }
}

// ---------------- stage 1: per-block partial histograms of q bits ----------------

__global__ void k_hist(const float* c0, const float* c1, const float* c2,
                       const float* t0, const float* t1, const float* t2,
                       unsigned int* parts, unsigned int* counters) {
    int level = blockIdx.z, img = blockIdx.y;
    int pair = img * NLVL + level;
    if (blockIdx.x == 0 && threadIdx.x == 0) counters[pair * 16] = 0;
    const float* cls; const float* ctr; int hw;
    lvl_select(level, c0, c1, c2, t0, t1, t2, &cls, &ctr, &hw);
    int n4 = hw * (NCLS / 4);          // float4 granules; 4 classes share one anchor
    const float4* cl4 = (const float4*)(cls + (size_t)img * hw * NCLS);
    const float* ct = ctr + (size_t)img * hw;
    __shared__ unsigned int h[HBINS];
    for (int i = threadIdx.x; i < HBINS; i += 256) h[i] = 0;
    __syncthreads();
    for (int i = blockIdx.x * 256 + threadIdx.x; i < n4; i += NHBLK * 256) {
        float4 v = cl4[i];
        int a = i / (NCLS / 4);        // 20 float4 per anchor row
        float eb = expf(-ct[a]);
        float t1 = __fadd_rn(1.f, eb);
        #pragma unroll
        for (int k = 0; k < 4; ++k) {
            float x = (k == 0) ? v.x : (k == 1) ? v.y : (k == 2) ? v.z : v.w;
            unsigned int qb = qbits(expf(-x), t1);
            if (qb < QMAX) {
                unsigned int bin = (qb - QBASE) >> 13;
                if (bin > HBINS - 1) bin = HBINS - 1;
                atomicAdd(&h[bin], 1u);
            }
        }
    }
    __syncthreads();
    unsigned int* P = parts + ((size_t)(pair * NHBLK + blockIdx.x)) * HBINS;
    for (int i = threadIdx.x; i < HBINS; i += 256) P[i] = h[i];   // coalesced, no atomics
}

// ---------------- stage 2 (fused): in-block cutoff find + collect ----------------

__global__ void k_collect(const float* c0, const float* c1, const float* c2,
                          const float* t0, const float* t1, const float* t2,
                          const unsigned int* parts, unsigned int* counters,
                          unsigned long long* buf) {
    int level = blockIdx.z, img = blockIdx.y;
    int pair = img * NLVL + level;
    int tid = threadIdx.x;
    __shared__ unsigned int hb[HBINS];          // 16 KB merged hist
    __shared__ unsigned int segsum[256];
    __shared__ unsigned int pref[256];
    __shared__ unsigned long long sbuf[CAP];    // 4 KB survivor staging
    __shared__ unsigned int scnt, sbase, Vsh;
    if (tid == 0) scnt = 0;
    {
        unsigned int acc[HBINS / 256];
        #pragma unroll
        for (int j = 0; j < HBINS / 256; ++j) acc[j] = 0;
        for (int blk = 0; blk < NHBLK; ++blk) {
            const unsigned int* P = parts + ((size_t)(pair * NHBLK + blk)) * HBINS;
            #pragma unroll
            for (int j = 0; j < HBINS / 256; ++j) acc[j] += P[tid + 256 * j];
        }
        #pragma unroll
        for (int j = 0; j < HBINS / 256; ++j) hb[tid + 256 * j] = acc[j];
    }
    __syncthreads();
    {
        unsigned int seg = 0;
        #pragma unroll
        for (int j = 0; j < 16; ++j) seg += hb[16 * tid + j];
        segsum[tid] = seg;
        pref[tid] = seg;
        __syncthreads();
        for (int off = 1; off < 256; off <<= 1) {
            unsigned int v = (tid >= off) ? pref[tid - off] : 0u;
            __syncthreads();
            pref[tid] += v;
            __syncthreads();
        }
        unsigned int incl = pref[tid];
        unsigned int excl = incl - segsum[tid];
        if (excl < (unsigned int)SELK && incl >= (unsigned int)SELK) {
            unsigned int cum = excl; int B = HBINS - 1;
            for (int b = 16 * tid; b < 16 * tid + 16; ++b) {
                cum += hb[b];
                if (cum >= (unsigned int)SELK) { B = b; break; }
            }
            Vsh = (B >= HBINS - 1) ? QMAX : (QBASE + ((unsigned int)(B + 1) << 13));
        }
        if (tid == 255 && pref[255] < (unsigned int)SELK)
            Vsh = QMAX;   // fewer than SELK pass threshold: collect all passing
    }
    __syncthreads();
    unsigned int V = Vsh;

    const float* cls; const float* ctr; int hw;
    lvl_select(level, c0, c1, c2, t0, t1, t2, &cls, &ctr, &hw);
    int n4 = hw * (NCLS / 4);
    const float4* cl4 = (const float4*)(cls + (size_t)img * hw * NCLS);
    const float* ct = ctr + (size_t)img * hw;
    for (int i = blockIdx.x * 256 + tid; i < n4; i += NCBLK * 256) {
        float4 v = cl4[i];
        int a = i / (NCLS / 4);
        float cta = ct[a];
        float eb = expf(-cta);
        float t1 = __fadd_rn(1.f, eb);
        #pragma unroll
        for (int k = 0; k < 4; ++k) {
            float x = (k == 0) ? v.x : (k == 1) ? v.y : (k == 2) ? v.z : v.w;
            unsigned int qb = qbits(expf(-x), t1);
            if (qb < V) {
                // exact score, bit-identical to rounds 1-11 (validated absmax 0.0)
                float s = sqrtf(sigm(x) * sigm(cta));
                unsigned int e = (unsigned int)(4 * i + k);          // < 2^19
                unsigned int p = ((unsigned int)level << 19) | e;    // 21-bit tie word
                unsigned int slot = atomicAdd(&scnt, 1u);   // LDS atomic, sparse
                if (slot < CAP)
                    sbuf[slot] = ((unsigned long long)__float_as_uint(s) << 32) | (~p);
            }
        }
    }
    __syncthreads();
    unsigned int cl_n = scnt; if (cl_n > CAP) cl_n = CAP;
    if (tid == 0)
        sbase = atomicAdd(&counters[pair * 16], cl_n);      // one global atomic/block
    __syncthreads();
    unsigned int base = sbase;
    for (unsigned int idx = tid; idx < cl_n; idx += 256) {
        unsigned int g = base + idx;
        if (g < CAP) buf[(size_t)pair * CAP + g] = sbuf[idx];   // coalesced flush
    }
}

// ---------------- stage 3: shfl-sort + merge + mask-precomputed NMS ----------------
// Round-11 postmortem: LDS bitonic (barriered OR volatile wave-sync) is ~25 us of
// pure LDS/barrier latency, and the single-wave NMS loops are ~15 us of unhidden
// LDS latency. Now: (a) 64-wide runs sorted IN REGISTERS via shfl (no LDS), then
// 3 merge-path rounds with 512 threads (latency hidden by 8 waves, 1 barrier each);
// (b) pairwise suppression masks for the first NMSW ranks precomputed in parallel,
// so the serial wave only reads 4 mask words per lane per batch.

__global__ void __launch_bounds__(512)
k_merge_nms(const unsigned long long* buf, const unsigned int* counters,
            const float* r0, const float* r1, const float* r2,
            const float* a0, const float* a1, const float* a2,
            float* out) {
    int img = blockIdx.x;
    int tid = threadIdx.x;
    int lane = tid & 63;
    __shared__ unsigned long long S[3 * CAP];   // 12 KB ping
    __shared__ unsigned long long T[3 * CAP];   // 12 KB pong
    __shared__ float4 wbox[NDEC];               // 8 KB decoded boxes
    __shared__ int    wlab[NDEC];               // 2 KB
    __shared__ float4 obx[NMSW];                // 4 KB offset boxes
    __shared__ float  oar[NMSW];                // 1 KB areas
    __shared__ unsigned long long colmask[NMSW][4];  // 8 KB suppression masks
    __shared__ float4 sbx[64]; __shared__ float sar[64];
    __shared__ float4 koff[DETS]; __shared__ float karr[DETS];
    __shared__ float4 kb[DETS]; __shared__ float ks[DETS]; __shared__ int kl[DETS];
    __shared__ float4 rb[DETS]; __shared__ int rl[DETS];

    // ---- phase A: load + in-register shfl bitonic sort of 64-wide runs ----
    unsigned long long v0, v1, v2;
    {
        int c0n = (int)counters[(img * NLVL + 0) * 16]; if (c0n > CAP) c0n = CAP;
        int c1n = (int)counters[(img * NLVL + 1) * 16]; if (c1n > CAP) c1n = CAP;
        int c2n = (int)counters[(img * NLVL + 2) * 16]; if (c2n > CAP) c2n = CAP;
        v0 = (tid < c0n) ? buf[(size_t)(img * NLVL + 0) * CAP + tid] : 0ull;
        v1 = (tid < c1n) ? buf[(size_t)(img * NLVL + 1) * CAP + tid] : 0ull;
        v2 = (tid < c2n) ? buf[(size_t)(img * NLVL + 2) * CAP + tid] : 0ull;
    }
    #pragma unroll
    for (int k = 2; k <= 64; k <<= 1) {
        #pragma unroll
        for (int j = k >> 1; j > 0; j >>= 1) {
            unsigned long long p0 = shfl_u64(v0, lane ^ j);
            unsigned long long p1 = shfl_u64(v1, lane ^ j);
            unsigned long long p2 = shfl_u64(v2, lane ^ j);
            bool up = ((lane & k) == 0);
            bool lower = ((lane & j) == 0);
            bool mx = (up == lower);
            v0 = mx ? (v0 > p0 ? v0 : p0) : (v0 < p0 ? v0 : p0);
            v1 = mx ? (v1 > p1 ? v1 : p1) : (v1 < p1 ? v1 : p1);
            v2 = mx ? (v2 > p2 ? v2 : p2) : (v2 < p2 ? v2 : p2);
        }
    }
    S[0 * CAP + tid] = v0;
    S[1 * CAP + tid] = v1;
    S[2 * CAP + tid] = v2;
    __syncthreads();

    // ---- phase B: 3 merge-path rounds (64->128->256->512), all segs concurrent ----
    {
        unsigned long long* src = S;
        unsigned long long* dst = T;
        for (int m = 64; m <= 256; m <<= 1) {
            for (int o = tid; o < 3 * CAP; o += 512) {
                int seg = o >> 9, k = o & (CAP - 1);
                int pw = 2 * m;
                int ab = seg * CAP + (k / pw) * pw;
                int q = k % pw;
                int lo = max(0, q - m), hi = min(q, m);
                while (lo < hi) {
                    int mid = (lo + hi) >> 1;
                    if (src[ab + mid] > src[ab + m + (q - mid - 1)]) lo = mid + 1; else hi = mid;
                }
                int i2 = lo, j2 = q - lo;
                unsigned long long av = (i2 < m) ? src[ab + i2] : 0ull;
                unsigned long long bv = (j2 < m) ? src[ab + m + j2] : 0ull;
                dst[o] = (av > bv) ? av : bv;
            }
            __syncthreads();
            unsigned long long* tmp = src; src = dst; dst = tmp;
        }
    }
    // after 3 rounds: sorted segments live in T (S->T->S->T)
    // merge-path A (512) + B (512) -> M (1024) in S
    for (int k = tid; k < 2 * CAP; k += 512) {
        int lo = max(0, k - CAP), hi = min(k, CAP);
        while (lo < hi) {
            int mid = (lo + hi) >> 1;
            if (T[mid] > T[CAP + (k - mid - 1)]) lo = mid + 1; else hi = mid;
        }
        int i = lo, j = k - lo;
        unsigned long long av = (i < CAP) ? T[i] : 0ull;
        unsigned long long bv = (j < CAP) ? T[CAP + j] : 0ull;
        S[k] = (av > bv) ? av : bv;
    }
    __syncthreads();
    // top-512 of merge(M (1024) in S, C (512) in T[2*CAP..]) -> S[0..512)
    {
        int k = tid;
        int lo = max(0, k - CAP), hi = k;
        while (lo < hi) {
            int mid = (lo + hi) >> 1;
            if (S[mid] > T[2 * CAP + (k - mid - 1)]) lo = mid + 1; else hi = mid;
        }
        int i = lo, j = k - lo;
        unsigned long long mv = (i < 2 * CAP) ? S[i] : 0ull;
        unsigned long long cv = (j < CAP) ? T[2 * CAP + j] : 0ull;
        unsigned long long rk = (mv > cv) ? mv : cv;
        __syncthreads();                    // all merge reads done before R write
        S[k] = rk;
    }
    __syncthreads();

    // ---- phase C: lazy decode of the top NDEC ranks ----
    {
        unsigned long long key = S[tid];
        float4 b4 = make_float4(0.f, 0.f, 0.f, 0.f); int lbv = 0;
        if (key != 0ull) {
            unsigned int p = (~((unsigned int)key)) & 0x1FFFFFu;
            int lvl = (int)(p >> 19);
            unsigned int e = p & 0x7FFFFu;
            int a = (int)(e / NCLS); lbv = (int)(e % NCLS);
            const float* anc; const float* reg; int hw;
            if (lvl == 0)      { anc = a0; reg = r0; hw = 4096; }
            else if (lvl == 1) { anc = a1; reg = r1; hw = 1024; }
            else               { anc = a2; reg = r2; hw = 256; }
            const float* rg = reg + (size_t)img * hw * 4;
            float ax1 = anc[a * 4 + 0], ay1 = anc[a * 4 + 1];
            float ax2 = anc[a * 4 + 2], ay2 = anc[a * 4 + 3];
            float cx = 0.5f * (ax1 + ax2), cy = 0.5f * (ay1 + ay2);
            float w = ax2 - ax1, h = ay2 - ay1;
            float e0 = rg[a * 4 + 0] * w, e1 = rg[a * 4 + 1] * h;
            float e2 = rg[a * 4 + 2] * w, e3 = rg[a * 4 + 3] * h;
            b4.x = fminf(fmaxf(cx - e0, 0.f), IMGSZ);
            b4.y = fminf(fmaxf(cy - e1, 0.f), IMGSZ);
            b4.z = fminf(fmaxf(cx + e2, 0.f), IMGSZ);
            b4.w = fminf(fmaxf(cy + e3, 0.f), IMGSZ);
        }
        wbox[tid] = b4; wlab[tid] = lbv;
    }
    __syncthreads();

    // ---- phase D: parallel offset boxes + pairwise suppression masks (NMSW ranks) ----
    if (tid < NMSW) {
        float4 bx = wbox[tid]; int lb = wlab[tid];
        float off = (float)lb * (IMGSZ + 1.0f);
        float ox1 = bx.x + off, oy1 = bx.y + off;
        float ox2 = bx.z + off, oy2 = bx.w + off;
        obx[tid] = make_float4(ox1, oy1, ox2, oy2);
        oar[tid] = (ox2 - ox1) * (oy2 - oy1);
    }
    __syncthreads();
    for (int Tk = tid; Tk < NMSW * 4; Tk += 512) {
        int j = Tk & (NMSW - 1);
        int w = Tk >> 8;                 // lanes of a wave share w; jj loop broadcasts
        float4 oj = obx[j]; float aj = oar[j];
        unsigned long long m = 0ull;
        int base = w * 64;
        for (int jj = 0; jj < 64; ++jj) {
            int i = base + jj;
            if (i < j) {
                float4 oi = obx[i]; float ai = oar[i];
                float lx = fmaxf(oi.x, oj.x), ly = fmaxf(oi.y, oj.y);
                float rx = fminf(oi.z, oj.z), ry = fminf(oi.w, oj.w);
                float ww = fmaxf(rx - lx, 0.f), hh = fmaxf(ry - ly, 0.f);
                float inter = ww * hh;
                if (inter / (ai + aj - inter) > 0.6f) m |= (1ull << jj);
            }
        }
        colmask[j][w] = m;
    }
    __syncthreads();

    if (tid >= 64) return;   // single wave finishes (mask-driven, short)
    unsigned long long lmask_lt = (lane == 0) ? 0ull : (~0ull >> (64 - lane));
    unsigned long long K[4] = {0ull, 0ull, 0ull, 0ull};   // kept masks per batch

    int kept = 0, ring = 0, r = 0;

    while (kept < DETS && r < NDEC) {
        int rank = r + lane;
        unsigned long long key = (rank < NDEC) ? S[rank] : 0ull;
        unsigned int bits = (unsigned int)(key >> 32);
        unsigned long long pm = __ballot(bits != 0u);   // positives form a prefix (sorted)
        int npos = (pm == ~0ull) ? 64 : (int)__builtin_ctzll(~pm);
        if (npos == 0) break;                           // negatives from rank r onward

        float4 bx = make_float4(0.f, 0.f, 0.f, 0.f); int lb = 0;
        if (lane < npos) { bx = wbox[rank]; lb = wlab[rank]; }
        float off = (float)lb * (IMGSZ + 1.0f);
        float ox1 = bx.x + off, oy1 = bx.y + off;
        float ox2 = bx.z + off, oy2 = bx.w + off;
        float car = (ox2 - ox1) * (oy2 - oy1);

        bool supk = false;
        unsigned long long col = 0ull;
        if (r < NMSW) {
            // mask path: batches are 64-aligned while r < NMSW (cap-cut exits loop;
            // a short batch from negatives is followed by npos==0 break)
            int b = r >> 6;
            int i = rank;            // < NMSW
            unsigned long long cm0 = colmask[i][0], cm1 = colmask[i][1];
            unsigned long long cm2 = colmask[i][2], cm3 = colmask[i][3];
            unsigned long long sup = 0ull;
            if (b > 0) sup |= cm0 & K[0];
            if (b > 1) sup |= cm1 & K[1];
            if (b > 2) sup |= cm2 & K[2];
            supk = sup != 0ull;
            col = (b == 0) ? cm0 : (b == 1) ? cm1 : (b == 2) ? cm2 : cm3;
        } else {
            // fallback (unreachable in practice: kept hits 100 by rank ~210)
            sbx[lane] = make_float4(ox1, oy1, ox2, oy2);
            sar[lane] = car;         // single wave: program-order LDS
            for (int k2 = 0; k2 < kept; ++k2) {
                float4 kk = koff[k2]; float ka = karr[k2];
                float lx = fmaxf(kk.x, ox1), ly = fmaxf(kk.y, oy1);
                float rx = fminf(kk.z, ox2), ry = fminf(kk.w, oy2);
                float w = fmaxf(rx - lx, 0.f), h = fmaxf(ry - ly, 0.f);
                float inter = w * h;
                supk = supk || (inter / (ka + car - inter) > 0.6f);
            }
            for (int i = 0; i < npos; ++i) {
                float4 c = sbx[i]; float ca = sar[i];
                float lx = fmaxf(c.x, ox1), ly = fmaxf(c.y, oy1);
                float rx = fminf(c.z, ox2), ry = fminf(c.w, oy2);
                float w = fmaxf(rx - lx, 0.f), h = fmaxf(ry - ly, 0.f);
                float inter = w * h;
                if ((inter / (ca + car - inter) > 0.6f) && (i < lane)) col |= (1ull << i);
            }
        }
        // wave-uniform greedy resolve (picks in increasing slot order) — validated
        unsigned long long undecided = __ballot((lane < npos) && !supk);
        unsigned long long aliveSel = 0ull;
        int capleft = DETS - kept;
        int lastSlot = npos - 1;
        while (undecided) {
            int i = (int)__builtin_ctzll(undecided);
            aliveSel |= (1ull << i);
            undecided &= ~(1ull << i);
            if (--capleft == 0) { lastSlot = i; break; }   // kept hits 100 at slot i
            unsigned long long row = __ballot(((col >> i) & 1ull) != 0ull);
            undecided &= ~row;
        }
        unsigned long long region = (lastSlot >= 63) ? ~0ull : ((1ull << (lastSlot + 1)) - 1ull);
        region &= (npos >= 64) ? ~0ull : ((1ull << npos) - 1ull);
        unsigned long long rejm = region & ~aliveSel;

        if (r < NMSW) K[r >> 6] = aliveSel;

        if ((aliveSel >> lane) & 1ull) {
            int ki = kept + (int)__popcll(aliveSel & lmask_lt);
            koff[ki] = make_float4(ox1, oy1, ox2, oy2); karr[ki] = car;
            kb[ki] = bx; ks[ki] = __uint_as_float(bits); kl[ki] = lb;
        }
        if ((rejm >> lane) & 1ull) {
            int ri = ring + (int)__popcll(rejm & lmask_lt);
            if (ri < DETS) { rb[ri] = bx; rl[ri] = lb; }
        }
        kept += (int)__popcll(aliveSel);
        ring += (int)__popcll(rejm);
        r += lastSlot + 1;
    }

    // negative / padding fill: remaining ranks in order until ring >= DETS
    while (kept < DETS && ring < DETS && r < NDEC) {
        int rank = r + lane;
        if (rank < NDEC) {
            int ri = ring + lane;
            if (ri < DETS) { rb[ri] = wbox[rank]; rl[ri] = wlab[rank]; }
        }
        int take = NDEC - r; if (take > 64) take = 64;
        ring += take;
        r += 64;
    }

    for (int k = lane; k < DETS; k += 64) {
        float4 bxo; float scv; int lv;
        if (k < kept) { bxo = kb[k]; scv = ks[k]; lv = kl[k]; }
        else { int q = k - kept; bxo = rb[q]; scv = -1.0f; lv = rl[q]; }
        float* ob = out + ((size_t)img * DETS + k) * 4;
        ob[0] = bxo.x; ob[1] = bxo.y; ob[2] = bxo.z; ob[3] = bxo.w;
        out[NIMG * DETS * 4 + img * DETS + k] = scv;
        out[NIMG * DETS * 5 + img * DETS + k] = (float)lv;
    }
}

// ---------------- launch ----------------

extern "C" void kernel_launch(void* const* d_in, const int* in_sizes, int n_in,
                              void* d_out, int out_size, void* d_ws, size_t ws_size,
                              hipStream_t stream) {
    (void)in_sizes; (void)n_in; (void)out_size; (void)ws_size;
    // setup_inputs() dict order: cls0, reg0, ctr0, anc0, cls1, reg1, ctr1, anc1, cls2, reg2, ctr2, anc2
    const float* cls0 = (const float*)d_in[0];
    const float* reg0 = (const float*)d_in[1];
    const float* ctr0 = (const float*)d_in[2];
    const float* anc0 = (const float*)d_in[3];
    const float* cls1 = (const float*)d_in[4];
    const float* reg1 = (const float*)d_in[5];
    const float* ctr1 = (const float*)d_in[6];
    const float* anc1 = (const float*)d_in[7];
    const float* cls2 = (const float*)d_in[8];
    const float* reg2 = (const float*)d_in[9];
    const float* ctr2 = (const float*)d_in[10];
    const float* anc2 = (const float*)d_in[11];
    float* out = (float*)d_out;
    char* ws = (char*)d_ws;

    // workspace layout (bytes)
    const size_t OFF_PARTS = 0;          // 24*16*4096*4 = 6,291,456 (fully overwritten)
    const size_t OFF_CNT   = 6291456;    // 24 counters, 64B apart = 1536 (zeroed by k_hist)
    const size_t OFF_BUF   = 6292992;    // 24*512*8 = 98,304 -> total 6,391,296

    unsigned int* parts = (unsigned int*)(ws + OFF_PARTS);
    unsigned int* cnt   = (unsigned int*)(ws + OFF_CNT);
    unsigned long long* buf = (unsigned long long*)(ws + OFF_BUF);

    k_hist<<<dim3(NHBLK, NIMG, NLVL), 256, 0, stream>>>(
        cls0, cls1, cls2, ctr0, ctr1, ctr2, parts, cnt);
    k_collect<<<dim3(NCBLK, NIMG, NLVL), 256, 0, stream>>>(
        cls0, cls1, cls2, ctr0, ctr1, ctr2, parts, cnt, buf);
    k_merge_nms<<<NIMG, 512, 0, stream>>>(buf, cnt, reg0, reg1, reg2,
                                          anc0, anc1, anc2, out);
}

// Round 13
// 162.461 us; speedup vs baseline: 1.1077x; 1.0039x over previous
//
#include <hip/hip_runtime.h>

#define NCLS  80
#define LLOC  48            // local per-block cutoff rank (global top-256 superset, +8 sigma)
#define SCAP  64            // per-block slab region (survivors <= ~50)
#define NLVL  3
#define NIMG  8
#define DETS  100
#define POOL  1024          // per-(img,level) slab width = 16 blocks * 64
#define NDEC  512           // ranks decoded for NMS (consumed ~110-210)
#define NMSW  256           // ranks with precomputed pairwise masks
#define HBINS 4096          // q-space bins, 8192-ulp granules
#define NHBLK 16            // blocks per (img,level) pair
#define QBASE 0x3F800000u   // bits of q = 1.0 (q > 1 always)
#define QMAX  0x41C80000u   // bits of 25.0; q < 25  <=>  s > 0.2
#define IMGSZ 2048.0f

// ---------------- helpers ----------------

__device__ __forceinline__ float sigm(float x) {
    if (x >= 0.f) return 1.f / (1.f + expf(-x));
    float e = expf(x);
    return e / (1.f + e);
}

// q = (1+e^-a)(1+e^-b), rounding pinned (identical bits in both passes)
__device__ __forceinline__ unsigned int qbits(float ea, float t1) {
    return __float_as_uint(__fmul_rn(__fadd_rn(1.f, ea), t1));
}

__device__ __forceinline__ unsigned long long shfl_u64(unsigned long long v, int lane) {
    int lo = (int)(unsigned int)v;
    int hi = (int)(unsigned int)(v >> 32);
    lo = __shfl(lo, lane, 64);
    hi = __shfl(hi, lane, 64);
    return ((unsigned long long)(unsigned int)hi << 32) | (unsigned int)lo;
}

__device__ __forceinline__ void lvl_select(int level,
    const float* c0, const float* c1, const float* c2,
    const float* t0, const float* t1, const float* t2,
    const float** cls, const float** ctr, int* hw) {
    if (level == 0)      { *cls = c0; *ctr = t0; *hw = 4096; }
    else if (level == 1) { *cls = c1; *ctr = t1; *hw = 1024; }
    else                 { *cls = c2; *ctr = t2; *hw = 256; }
}

// ---------------- stage 1 (fused): local hist -> local cutoff -> collect ----------------
// Each block histograms ITS stripe, picks V at LOCAL rank LLOC (union of local
// top-48s is a superset of the pair's global top-256: Binomial(256,1/16) mean 16,
// 48 = +8 sigma), then re-scans its L2-hot stripe collecting survivors into a
// FIXED 64-slot slab region (no counters, no global atomics, no memset).
// Key is GLOBALLY comparable: (score_bits << 32) | ~((level<<19)|e) — for equal
// score bits the reference global order is (level asc, flat-index asc).

__global__ void k_histcollect(const float* c0, const float* c1, const float* c2,
                              const float* t0, const float* t1, const float* t2,
                              unsigned long long* slab) {
    int level = blockIdx.z, img = blockIdx.y;
    int pair = img * NLVL + level;
    int tid = threadIdx.x;
    const float* cls; const float* ctr; int hw;
    lvl_select(level, c0, c1, c2, t0, t1, t2, &cls, &ctr, &hw);
    int n4 = hw * (NCLS / 4);          // float4 granules; 4 classes share one anchor
    const float4* cl4 = (const float4*)(cls + (size_t)img * hw * NCLS);
    const float* ct = ctr + (size_t)img * hw;
    __shared__ unsigned int h[HBINS];          // 16 KB local hist
    __shared__ unsigned int segsum[256];
    __shared__ unsigned int pref[256];
    __shared__ unsigned long long sbuf[SCAP];  // 512 B survivor staging
    __shared__ unsigned int scnt, Vsh;
    if (tid == 0) scnt = 0;
    for (int i = tid; i < HBINS; i += 256) h[i] = 0;
    __syncthreads();
    // pass 1: histogram of q bits over this block's stripe
    for (int i = blockIdx.x * 256 + tid; i < n4; i += NHBLK * 256) {
        float4 v = cl4[i];
        int a = i / (NCLS / 4);        // 20 float4 per anchor row
        float eb = expf(-ct[a]);
        float t1 = __fadd_rn(1.f, eb);
        #pragma unroll
        for (int k = 0; k < 4; ++k) {
            float x = (k == 0) ? v.x : (k == 1) ? v.y : (k == 2) ? v.z : v.w;
            unsigned int qb = qbits(expf(-x), t1);
            if (qb < QMAX) {
                unsigned int bin = (qb - QBASE) >> 13;
                if (bin > HBINS - 1) bin = HBINS - 1;
                atomicAdd(&h[bin], 1u);
            }
        }
    }
    __syncthreads();
    // local scan: q ascending == score descending; bracket LOCAL rank LLOC
    {
        unsigned int seg = 0;
        #pragma unroll
        for (int j = 0; j < 16; ++j) seg += h[16 * tid + j];
        segsum[tid] = seg;
        pref[tid] = seg;
        __syncthreads();
        for (int off = 1; off < 256; off <<= 1) {
            unsigned int v = (tid >= off) ? pref[tid - off] : 0u;
            __syncthreads();
            pref[tid] += v;
            __syncthreads();
        }
        unsigned int incl = pref[tid];
        unsigned int excl = incl - segsum[tid];
        if (excl < (unsigned int)LLOC && incl >= (unsigned int)LLOC) {
            unsigned int cum = excl; int B = HBINS - 1;
            for (int b = 16 * tid; b < 16 * tid + 16; ++b) {
                cum += h[b];
                if (cum >= (unsigned int)LLOC) { B = b; break; }
            }
            Vsh = (B >= HBINS - 1) ? QMAX : (QBASE + ((unsigned int)(B + 1) << 13));
        }
        if (tid == 255 && pref[255] < (unsigned int)LLOC)
            Vsh = QMAX;   // fewer than LLOC pass threshold locally: collect all passing
    }
    __syncthreads();
    unsigned int V = Vsh;
    // pass 2: collect survivors (stripe is L2-hot from pass 1)
    for (int i = blockIdx.x * 256 + tid; i < n4; i += NHBLK * 256) {
        float4 v = cl4[i];
        int a = i / (NCLS / 4);
        float cta = ct[a];
        float eb = expf(-cta);
        float t1 = __fadd_rn(1.f, eb);
        #pragma unroll
        for (int k = 0; k < 4; ++k) {
            float x = (k == 0) ? v.x : (k == 1) ? v.y : (k == 2) ? v.z : v.w;
            unsigned int qb = qbits(expf(-x), t1);
            if (qb < V) {
                // exact score, bit-identical to rounds 1-12 (validated absmax 0.0)
                float s = sqrtf(sigm(x) * sigm(cta));
                unsigned int e = (unsigned int)(4 * i + k);          // < 2^19
                unsigned int p = ((unsigned int)level << 19) | e;    // 21-bit tie word
                unsigned int slot = atomicAdd(&scnt, 1u);   // LDS atomic, sparse
                if (slot < SCAP)
                    sbuf[slot] = ((unsigned long long)__float_as_uint(s) << 32) | (~p);
            }
        }
    }
    __syncthreads();
    unsigned int n = scnt; if (n > SCAP) n = SCAP;
    unsigned long long* o = slab + ((size_t)(pair * NHBLK + blockIdx.x)) * SCAP;
    for (unsigned int idx = tid; idx < SCAP; idx += 256)
        o[idx] = (idx < n) ? sbuf[idx] : 0ull;   // zero-pad own fixed region
}

// ---------------- stage 2: shfl-sort pools + merge + mask-precomputed NMS ----------------
// One block (512 thr, 8 waves) per image. Pools are now 1024 wide (16 blocks x 64
// fixed slots, zero-padded). Sort: 64-wide runs in REGISTERS via shfl (6 regs:
// 3 pools x 2 runs/thread), then 4 concurrent merge-path rounds (64->1024,
// 1 barrier each), two top-512 cross-pool merge-paths, then the validated
// decode + pairwise-mask + ballot/ctz greedy resolve (byte-identical to R12).

__global__ void __launch_bounds__(512)
k_merge_nms(const unsigned long long* slab,
            const float* r0, const float* r1, const float* r2,
            const float* a0, const float* a1, const float* a2,
            float* out) {
    int img = blockIdx.x;
    int tid = threadIdx.x;
    int lane = tid & 63;
    int w = tid >> 6;                            // wave 0..7
    __shared__ __align__(16) unsigned long long W0[3 * POOL];   // 24 KB ping (aliased later)
    __shared__ __align__(16) unsigned long long W1[3 * POOL];   // 24 KB pong; holds R
    __shared__ float4 sbx[64]; __shared__ float sar[64];
    __shared__ float4 koff[DETS]; __shared__ float karr[DETS];
    __shared__ float4 kb[DETS]; __shared__ float ks[DETS]; __shared__ int kl[DETS];
    __shared__ float4 rb[DETS]; __shared__ int rl[DETS];
    // aliases into W0 (dead after the merge rounds)
    float4* wbox = (float4*)W0;                                  // 512*16 = 8 KB
    int*    wlab = (int*)((char*)W0 + 8192);                     // 2 KB
    float4* obx  = (float4*)((char*)W0 + 10240);                 // 4 KB
    float*  oar  = (float*)((char*)W0 + 14336);                  // 1 KB
    unsigned long long (*colmask)[4] =
        (unsigned long long (*)[4])((char*)W0 + 15360);          // 8 KB -> ends 23552

    // ---- phase A: load 6 runs/thread + in-register shfl bitonic sort ----
    const unsigned long long* SL = slab + (size_t)img * NLVL * POOL;
    unsigned long long v00 = SL[0 * POOL + (w    ) * 64 + lane];
    unsigned long long v01 = SL[0 * POOL + (w + 8) * 64 + lane];
    unsigned long long v10 = SL[1 * POOL + (w    ) * 64 + lane];
    unsigned long long v11 = SL[1 * POOL + (w + 8) * 64 + lane];
    unsigned long long v20 = SL[2 * POOL + (w    ) * 64 + lane];
    unsigned long long v21 = SL[2 * POOL + (w + 8) * 64 + lane];
    #pragma unroll
    for (int k = 2; k <= 64; k <<= 1) {
        #pragma unroll
        for (int j = k >> 1; j > 0; j >>= 1) {
            unsigned long long p00 = shfl_u64(v00, lane ^ j);
            unsigned long long p01 = shfl_u64(v01, lane ^ j);
            unsigned long long p10 = shfl_u64(v10, lane ^ j);
            unsigned long long p11 = shfl_u64(v11, lane ^ j);
            unsigned long long p20 = shfl_u64(v20, lane ^ j);
            unsigned long long p21 = shfl_u64(v21, lane ^ j);
            bool up = ((lane & k) == 0);
            bool lower = ((lane & j) == 0);
            bool mx = (up == lower);
            v00 = mx ? (v00 > p00 ? v00 : p00) : (v00 < p00 ? v00 : p00);
            v01 = mx ? (v01 > p01 ? v01 : p01) : (v01 < p01 ? v01 : p01);
            v10 = mx ? (v10 > p10 ? v10 : p10) : (v10 < p10 ? v10 : p10);
            v11 = mx ? (v11 > p11 ? v11 : p11) : (v11 < p11 ? v11 : p11);
            v20 = mx ? (v20 > p20 ? v20 : p20) : (v20 < p20 ? v20 : p20);
            v21 = mx ? (v21 > p21 ? v21 : p21) : (v21 < p21 ? v21 : p21);
        }
    }
    W1[0 * POOL + (w    ) * 64 + lane] = v00;
    W1[0 * POOL + (w + 8) * 64 + lane] = v01;
    W1[1 * POOL + (w    ) * 64 + lane] = v10;
    W1[1 * POOL + (w + 8) * 64 + lane] = v11;
    W1[2 * POOL + (w    ) * 64 + lane] = v20;
    W1[2 * POOL + (w + 8) * 64 + lane] = v21;

    // ---- phase B: 4 merge-path rounds (64->1024), all pools concurrent ----
    {
        unsigned long long* src = W1;
        unsigned long long* dst = W0;
        for (int m = 64; m <= 512; m <<= 1) {
            __syncthreads();
            for (int o = tid; o < 3 * POOL; o += 512) {
                int seg = o >> 10, k = o & (POOL - 1);
                int pw = 2 * m;
                int ab = seg * POOL + (k & ~(pw - 1));
                int q = k & (pw - 1);
                int lo = max(0, q - m), hi = min(q, m);
                while (lo < hi) {
                    int mid = (lo + hi) >> 1;
                    if (src[ab + mid] > src[ab + m + (q - mid - 1)]) lo = mid + 1; else hi = mid;
                }
                int i2 = lo, j2 = q - lo;
                unsigned long long av = (i2 < m) ? src[ab + i2] : 0ull;
                unsigned long long bv = (j2 < m) ? src[ab + m + j2] : 0ull;
                dst[o] = (av > bv) ? av : bv;
            }
            unsigned long long* tmp = src; src = dst; dst = tmp;
        }
    }
    __syncthreads();        // sorted pools in W1: A|B|C, 1024 each
    // top-512 of merge(A, B) -> W1[0..512) (all reads land in [0,512) of each pool)
    {
        int k = tid;
        int lo = 0, hi = k;
        while (lo < hi) {
            int mid = (lo + hi) >> 1;
            if (W1[mid] > W1[POOL + (k - mid - 1)]) lo = mid + 1; else hi = mid;
        }
        int i = lo, j = k - lo;
        unsigned long long av = W1[i];
        unsigned long long bv = W1[POOL + j];
        unsigned long long rk = (av > bv) ? av : bv;
        __syncthreads();
        W1[k] = rk;
    }
    __syncthreads();
    // top-512 of merge(R0 = W1[0..512), C) -> R = W1[POOL .. POOL+512)
    {
        int k = tid;
        int lo = 0, hi = k;     // hi = min(k, 512) = k
        while (lo < hi) {
            int mid = (lo + hi) >> 1;
            if (W1[mid] > W1[2 * POOL + (k - mid - 1)]) lo = mid + 1; else hi = mid;
        }
        int i = lo, j = k - lo;
        unsigned long long av = (i < 512) ? W1[i] : 0ull;
        unsigned long long bv = W1[2 * POOL + j];
        unsigned long long rk = (av > bv) ? av : bv;
        __syncthreads();
        W1[POOL + k] = rk;      // R; B-region is dead
    }
    __syncthreads();

    // ---- phase C: lazy decode of the top NDEC ranks (W0 aliases now safe) ----
    {
        unsigned long long key = W1[POOL + tid];
        float4 b4 = make_float4(0.f, 0.f, 0.f, 0.f); int lbv = 0;
        if (key != 0ull) {
            unsigned int p = (~((unsigned int)key)) & 0x1FFFFFu;
            int lvl = (int)(p >> 19);
            unsigned int e = p & 0x7FFFFu;
            int a = (int)(e / NCLS); lbv = (int)(e % NCLS);
            const float* anc; const float* reg; int hw;
            if (lvl == 0)      { anc = a0; reg = r0; hw = 4096; }
            else if (lvl == 1) { anc = a1; reg = r1; hw = 1024; }
            else               { anc = a2; reg = r2; hw = 256; }
            const float* rg = reg + (size_t)img * hw * 4;
            float ax1 = anc[a * 4 + 0], ay1 = anc[a * 4 + 1];
            float ax2 = anc[a * 4 + 2], ay2 = anc[a * 4 + 3];
            float cx = 0.5f * (ax1 + ax2), cy = 0.5f * (ay1 + ay2);
            float w2 = ax2 - ax1, h2 = ay2 - ay1;
            float e0 = rg[a * 4 + 0] * w2, e1 = rg[a * 4 + 1] * h2;
            float e2 = rg[a * 4 + 2] * w2, e3 = rg[a * 4 + 3] * h2;
            b4.x = fminf(fmaxf(cx - e0, 0.f), IMGSZ);
            b4.y = fminf(fmaxf(cy - e1, 0.f), IMGSZ);
            b4.z = fminf(fmaxf(cx + e2, 0.f), IMGSZ);
            b4.w = fminf(fmaxf(cy + e3, 0.f), IMGSZ);
        }
        wbox[tid] = b4; wlab[tid] = lbv;
    }
    __syncthreads();

    // ---- phase D: parallel offset boxes + pairwise suppression masks ----
    if (tid < NMSW) {
        float4 bx = wbox[tid]; int lb = wlab[tid];
        float off = (float)lb * (IMGSZ + 1.0f);
        float ox1 = bx.x + off, oy1 = bx.y + off;
        float ox2 = bx.z + off, oy2 = bx.w + off;
        obx[tid] = make_float4(ox1, oy1, ox2, oy2);
        oar[tid] = (ox2 - ox1) * (oy2 - oy1);
    }
    __syncthreads();
    for (int Tk = tid; Tk < NMSW * 4; Tk += 512) {
        int j = Tk & (NMSW - 1);
        int wq = Tk >> 8;                // lanes of a wave share wq; jj loop broadcasts
        float4 oj = obx[j]; float aj = oar[j];
        unsigned long long m = 0ull;
        int base = wq * 64;
        for (int jj = 0; jj < 64; ++jj) {
            int i = base + jj;
            if (i < j) {
                float4 oi = obx[i]; float ai = oar[i];
                float lx = fmaxf(oi.x, oj.x), ly = fmaxf(oi.y, oj.y);
                float rx = fminf(oi.z, oj.z), ry = fminf(oi.w, oj.w);
                float ww = fmaxf(rx - lx, 0.f), hh = fmaxf(ry - ly, 0.f);
                float inter = ww * hh;
                if (inter / (ai + aj - inter) > 0.6f) m |= (1ull << jj);
            }
        }
        colmask[j][wq] = m;
    }
    __syncthreads();

    if (tid >= 64) return;   // single wave finishes (mask-driven, short)
    unsigned long long lmask_lt = (lane == 0) ? 0ull : (~0ull >> (64 - lane));
    unsigned long long K[4] = {0ull, 0ull, 0ull, 0ull};   // kept masks per batch

    int kept = 0, ring = 0, r = 0;

    while (kept < DETS && r < NDEC) {
        int rank = r + lane;
        unsigned long long key = (rank < NDEC) ? W1[POOL + rank] : 0ull;
        unsigned int bits = (unsigned int)(key >> 32);
        unsigned long long pm = __ballot(bits != 0u);   // positives form a prefix (sorted)
        int npos = (pm == ~0ull) ? 64 : (int)__builtin_ctzll(~pm);
        if (npos == 0) break;                           // negatives from rank r onward

        float4 bx = make_float4(0.f, 0.f, 0.f, 0.f); int lb = 0;
        if (lane < npos) { bx = wbox[rank]; lb = wlab[rank]; }
        float off = (float)lb * (IMGSZ + 1.0f);
        float ox1 = bx.x + off, oy1 = bx.y + off;
        float ox2 = bx.z + off, oy2 = bx.w + off;
        float car = (ox2 - ox1) * (oy2 - oy1);

        bool supk = false;
        unsigned long long col = 0ull;
        if (r < NMSW) {
            // mask path: batches are 64-aligned while r < NMSW
            int b = r >> 6;
            int i = rank;            // < NMSW
            unsigned long long cm0 = colmask[i][0], cm1 = colmask[i][1];
            unsigned long long cm2 = colmask[i][2], cm3 = colmask[i][3];
            unsigned long long sup = 0ull;
            if (b > 0) sup |= cm0 & K[0];
            if (b > 1) sup |= cm1 & K[1];
            if (b > 2) sup |= cm2 & K[2];
            supk = sup != 0ull;
            col = (b == 0) ? cm0 : (b == 1) ? cm1 : (b == 2) ? cm2 : cm3;
        } else {
            // fallback (unreachable in practice: kept hits 100 by rank ~210)
            sbx[lane] = make_float4(ox1, oy1, ox2, oy2);
            sar[lane] = car;         // single wave: program-order LDS
            for (int k2 = 0; k2 < kept; ++k2) {
                float4 kk = koff[k2]; float ka = karr[k2];
                float lx = fmaxf(kk.x, ox1), ly = fmaxf(kk.y, oy1);
                float rx = fminf(kk.z, ox2), ry = fminf(kk.w, oy2);
                float w2 = fmaxf(rx - lx, 0.f), h2 = fmaxf(ry - ly, 0.f);
                float inter = w2 * h2;
                supk = supk || (inter / (ka + car - inter) > 0.6f);
            }
            for (int i = 0; i < npos; ++i) {
                float4 c = sbx[i]; float ca = sar[i];
                float lx = fmaxf(c.x, ox1), ly = fmaxf(c.y, oy1);
                float rx = fminf(c.z, ox2), ry = fminf(c.w, oy2);
                float w2 = fmaxf(rx - lx, 0.f), h2 = fmaxf(ry - ly, 0.f);
                float inter = w2 * h2;
                if ((inter / (ca + car - inter) > 0.6f) && (i < lane)) col |= (1ull << i);
            }
        }
        // wave-uniform greedy resolve (picks in increasing slot order) — validated
        unsigned long long undecided = __ballot((lane < npos) && !supk);
        unsigned long long aliveSel = 0ull;
        int capleft = DETS - kept;
        int lastSlot = npos - 1;
        while (undecided) {
            int i = (int)__builtin_ctzll(undecided);
            aliveSel |= (1ull << i);
            undecided &= ~(1ull << i);
            if (--capleft == 0) { lastSlot = i; break; }   // kept hits 100 at slot i
            unsigned long long row = __ballot(((col >> i) & 1ull) != 0ull);
            undecided &= ~row;
        }
        unsigned long long region = (lastSlot >= 63) ? ~0ull : ((1ull << (lastSlot + 1)) - 1ull);
        region &= (npos >= 64) ? ~0ull : ((1ull << npos) - 1ull);
        unsigned long long rejm = region & ~aliveSel;

        if (r < NMSW) K[r >> 6] = aliveSel;

        if ((aliveSel >> lane) & 1ull) {
            int ki = kept + (int)__popcll(aliveSel & lmask_lt);
            koff[ki] = make_float4(ox1, oy1, ox2, oy2); karr[ki] = car;
            kb[ki] = bx; ks[ki] = __uint_as_float(bits); kl[ki] = lb;
        }
        if ((rejm >> lane) & 1ull) {
            int ri = ring + (int)__popcll(rejm & lmask_lt);
            if (ri < DETS) { rb[ri] = bx; rl[ri] = lb; }
        }
        kept += (int)__popcll(aliveSel);
        ring += (int)__popcll(rejm);
        r += lastSlot + 1;
    }

    // negative / padding fill: remaining ranks in order until ring >= DETS
    while (kept < DETS && ring < DETS && r < NDEC) {
        int rank = r + lane;
        if (rank < NDEC) {
            int ri = ring + lane;
            if (ri < DETS) { rb[ri] = wbox[rank]; rl[ri] = wlab[rank]; }
        }
        int take = NDEC - r; if (take > 64) take = 64;
        ring += take;
        r += 64;
    }

    for (int k = lane; k < DETS; k += 64) {
        float4 bxo; float scv; int lv;
        if (k < kept) { bxo = kb[k]; scv = ks[k]; lv = kl[k]; }
        else { int q = k - kept; bxo = rb[q]; scv = -1.0f; lv = rl[q]; }
        float* ob = out + ((size_t)img * DETS + k) * 4;
        ob[0] = bxo.x; ob[1] = bxo.y; ob[2] = bxo.z; ob[3] = bxo.w;
        out[NIMG * DETS * 4 + img * DETS + k] = scv;
        out[NIMG * DETS * 5 + img * DETS + k] = (float)lv;
    }
}

// ---------------- launch ----------------

extern "C" void kernel_launch(void* const* d_in, const int* in_sizes, int n_in,
                              void* d_out, int out_size, void* d_ws, size_t ws_size,
                              hipStream_t stream) {
    (void)in_sizes; (void)n_in; (void)out_size; (void)ws_size;
    // setup_inputs() dict order: cls0, reg0, ctr0, anc0, cls1, reg1, ctr1, anc1, cls2, reg2, ctr2, anc2
    const float* cls0 = (const float*)d_in[0];
    const float* reg0 = (const float*)d_in[1];
    const float* ctr0 = (const float*)d_in[2];
    const float* anc0 = (const float*)d_in[3];
    const float* cls1 = (const float*)d_in[4];
    const float* reg1 = (const float*)d_in[5];
    const float* ctr1 = (const float*)d_in[6];
    const float* anc1 = (const float*)d_in[7];
    const float* cls2 = (const float*)d_in[8];
    const float* reg2 = (const float*)d_in[9];
    const float* ctr2 = (const float*)d_in[10];
    const float* anc2 = (const float*)d_in[11];
    float* out = (float*)d_out;
    char* ws = (char*)d_ws;

    // workspace: slab only — 24 pairs * 1024 slots * 8 B = 196,608 bytes,
    // fully written by k_histcollect (fixed per-block regions, zero-padded).
    unsigned long long* slab = (unsigned long long*)ws;

    k_histcollect<<<dim3(NHBLK, NIMG, NLVL), 256, 0, stream>>>(
        cls0, cls1, cls2, ctr0, ctr1, ctr2, slab);
    k_merge_nms<<<NIMG, 512, 0, stream>>>(slab, reg0, reg1, reg2,
                                          anc0, anc1, anc2, out);
}